// Round 4
// baseline (1511.544 us; speedup 1.0000x reference)
//
#include <hip/hip_runtime.h>
#include <math.h>

// N=100000 nodes, D=128 feats, E=1600000 edges.
// f = alpha*(Ax - x) + beta*(-(x-1)*x) + clip(src*x0,-1,1)*0.1,  Ax[row] += w*x[col]
//
// R4: bucket-grouped (not row-sorted) edge layout.
//   R3's fill was sector-write-bound: 1.6M scattered 8B stores -> 101 MB of 64B
//   sector write-through at ~0.8 TB/s = 143 us. Fix: bin edges by 128-row bucket
//   with LDS staging so global writes are bucket-contiguous runs (~84 B avg).
//   Gather then accumulates each bucket into a 64 KB LDS out-tile with ds_add_f32
//   (no per-row CSR, no per-row sort), epilogue fused.
//
//   K0 zero(bucket_cnt) -> K1 bhist -> K2 bscan -> K3 binscatter -> K4 bgather

#define D_FEAT 128
#define RPB 128              // rows per bucket
#define MAXNB 1024           // supports N <= 131072 (here N=100000 -> NB=782)
#define K3_TILE 8192
#define K3_THREADS 1024
#define K4_THREADS 512
#define K4_CHUNK 512

__device__ __forceinline__ float sigmoid_f(float v) {
    return 1.0f / (1.0f + __expf(-v));
}

__global__ void zero_kernel(int* __restrict__ p, int n) {
    int i = blockIdx.x * blockDim.x + threadIdx.x;
    if (i < n) p[i] = 0;
}

// K1: LDS-staged bucket histogram. 4 edges/thread via int4, grid-stride.
__global__ void bhist_kernel(const int* __restrict__ rows, int* __restrict__ gcnt,
                             int E4, int NB) {
    __shared__ int lh[MAXNB];
    for (int i = threadIdx.x; i < NB; i += blockDim.x) lh[i] = 0;
    __syncthreads();
    int stride = gridDim.x * blockDim.x;
    for (int i = blockIdx.x * blockDim.x + threadIdx.x; i < E4; i += stride) {
        int4 r = ((const int4*)rows)[i];
        atomicAdd(&lh[r.x >> 7], 1);
        atomicAdd(&lh[r.y >> 7], 1);
        atomicAdd(&lh[r.z >> 7], 1);
        atomicAdd(&lh[r.w >> 7], 1);
    }
    __syncthreads();
    for (int i = threadIdx.x; i < NB; i += blockDim.x) {
        int v = lh[i];
        if (v) atomicAdd(&gcnt[i], v);
    }
}

// K2: one-wave exclusive scan of bucket counts -> off[0..NB], and cur[] copy.
__global__ void bscan_kernel(const int* __restrict__ cnt, int* __restrict__ off,
                             int* __restrict__ cur, int NB) {
    int lane = threadIdx.x;   // 64 threads
    int carry = 0;
    for (int base = 0; base < NB; base += 64) {
        int idx = base + lane;
        int v = (idx < NB) ? cnt[idx] : 0;
        int incl = v;
#pragma unroll
        for (int d = 1; d < 64; d <<= 1) {
            int t = __shfl_up(incl, d);
            if (lane >= d) incl += t;
        }
        int total = __shfl(incl, 63);
        int excl = incl - v + carry;
        if (idx < NB) { off[idx] = excl; cur[idx] = excl; }
        carry += total;
    }
    if (lane == 0) off[NB] = carry;
}

// K3: bin a tile of K3_TILE edges by bucket in LDS, then write bucket-contiguous
// runs to global. Record: meta = (local_row<<20)|col, payload = w*alpha (f32).
__global__ __launch_bounds__(K3_THREADS)
void binscatter_kernel(const int* __restrict__ rows, const int* __restrict__ cols,
                       const float* __restrict__ w, const float* __restrict__ alpha_p,
                       int* __restrict__ bucket_cur, uint2* __restrict__ recs,
                       int E, int NB) {
    __shared__ uint2 staged[K3_TILE];            // 64 KB
    __shared__ unsigned short sbid[K3_TILE];     // 16 KB
    __shared__ int hist[MAXNB];                  // 4 KB
    __shared__ int lstart[MAXNB];                // 4 KB
    __shared__ int gbase[MAXNB];                 // 4 KB
    __shared__ int cursor[MAXNB];                // 4 KB

    const float alpha = sigmoid_f(alpha_p[0]) * 0.1f;
    const int tid = threadIdx.x;
    const int tile0 = blockIdx.x * K3_TILE;
    const int nloc = min(K3_TILE, E - tile0);

    for (int i = tid; i < NB; i += K3_THREADS) hist[i] = 0;
    __syncthreads();

    // stage A: tile histogram
    for (int k = tid; k < nloc; k += K3_THREADS) {
        atomicAdd(&hist[rows[tile0 + k] >> 7], 1);
    }
    __syncthreads();

    // stage B: reserve global space per bucket (all threads, coalesced atomics)
    for (int i = tid; i < NB; i += K3_THREADS) {
        gbase[i] = atomicAdd(&bucket_cur[i], hist[i]);
    }
    // wave 0: exclusive scan hist -> lstart
    if (tid < 64) {
        int lane = tid;
        int carry = 0;
        for (int base = 0; base < NB; base += 64) {
            int idx = base + lane;
            int v = (idx < NB) ? hist[idx] : 0;
            int incl = v;
#pragma unroll
            for (int d = 1; d < 64; d <<= 1) {
                int t = __shfl_up(incl, d);
                if (lane >= d) incl += t;
            }
            int total = __shfl(incl, 63);
            if (idx < NB) lstart[idx] = incl - v + carry;
            carry += total;
        }
    }
    __syncthreads();
    for (int i = tid; i < NB; i += K3_THREADS) cursor[i] = lstart[i];
    __syncthreads();

    // stage C: place records into LDS grouped by bucket
    for (int k = tid; k < nloc; k += K3_THREADS) {
        int e = tile0 + k;
        int r = rows[e];
        int b = r >> 7;
        int p = atomicAdd(&cursor[b], 1);
        unsigned meta = ((unsigned)(r & (RPB - 1)) << 20) | (unsigned)cols[e];
        staged[p] = make_uint2(meta, __float_as_uint(w[e] * alpha));
        sbid[p] = (unsigned short)b;
    }
    __syncthreads();

    // stage D: write grouped records to global (run-coalesced)
    for (int s = tid; s < nloc; s += K3_THREADS) {
        int b = sbid[s];
        int gaddr = gbase[b] + (s - lstart[b]);
        recs[gaddr] = staged[s];
    }
}

// K4: one block per bucket. LDS out-tile 128 rows x 128 f32; ds_add_f32
// accumulation; fused elementwise epilogue; coalesced float4 write.
__global__ __launch_bounds__(K4_THREADS)
void bgather_kernel(const float* __restrict__ x, const float* __restrict__ x0,
                    const int* __restrict__ off, const uint2* __restrict__ recs,
                    const float* __restrict__ alpha_p, const float* __restrict__ beta_p,
                    const float* __restrict__ src_p, float* __restrict__ out, int N) {
    __shared__ float tile[RPB * D_FEAT];    // 64 KB
    __shared__ uint2 rbuf[K4_CHUNK];        // 4 KB

    const int b = blockIdx.x;
    const int tid = threadIdx.x;
    const int row0 = b << 7;
    const int nrows = min(RPB, N - row0);
    const int wave = tid >> 6;
    const int lane = tid & 63;

    for (int i = tid; i < RPB * D_FEAT / 4; i += K4_THREADS)
        ((float4*)tile)[i] = make_float4(0.f, 0.f, 0.f, 0.f);

    const int start = off[b];
    const int end = off[b + 1];
    const float2* x2 = (const float2*)x;

    for (int cbase = start; cbase < end; cbase += K4_CHUNK) {
        int clen = min(K4_CHUNK, end - cbase);
        __syncthreads();   // rbuf reuse safe; also covers tile zero on first iter
        if (tid < clen) rbuf[tid] = recs[cbase + tid];
        __syncthreads();

        int i = wave;
        for (; i + 8 < clen; i += 16) {
            uint2 r0 = rbuf[i];
            uint2 r1 = rbuf[i + 8];
            int c0 = r0.x & 0xFFFFF, lr0 = (int)(r0.x >> 20);
            int c1 = r1.x & 0xFFFFF, lr1 = (int)(r1.x >> 20);
            float2 v0 = x2[c0 * 64 + lane];
            float2 v1 = x2[c1 * 64 + lane];
            float w0 = __uint_as_float(r0.y);
            float w1 = __uint_as_float(r1.y);
            atomicAdd(&tile[lr0 * D_FEAT + lane * 2],     w0 * v0.x);
            atomicAdd(&tile[lr0 * D_FEAT + lane * 2 + 1], w0 * v0.y);
            atomicAdd(&tile[lr1 * D_FEAT + lane * 2],     w1 * v1.x);
            atomicAdd(&tile[lr1 * D_FEAT + lane * 2 + 1], w1 * v1.y);
        }
        if (i < clen) {
            uint2 r0 = rbuf[i];
            int c0 = r0.x & 0xFFFFF, lr0 = (int)(r0.x >> 20);
            float2 v0 = x2[c0 * 64 + lane];
            float w0 = __uint_as_float(r0.y);
            atomicAdd(&tile[lr0 * D_FEAT + lane * 2],     w0 * v0.x);
            atomicAdd(&tile[lr0 * D_FEAT + lane * 2 + 1], w0 * v0.y);
        }
    }
    __syncthreads();

    // epilogue: out = tile - alpha*x - beta*(x-1)*x + clip(src*x0,-1,1)*0.1
    const float alpha = sigmoid_f(alpha_p[0]) * 0.1f;
    const float beta  = sigmoid_f(beta_p[0]) * 0.1f;
    const float src   = src_p[0];

    int total4 = nrows * (D_FEAT / 4);
    for (int i = tid; i < total4; i += K4_THREADS) {
        int gidx = row0 * (D_FEAT / 4) + i;
        float4 xv  = ((const float4*)x)[gidx];
        float4 x0v = ((const float4*)x0)[gidx];
        float4 a   = ((float4*)tile)[i];
        float xs[4] = {xv.x, xv.y, xv.z, xv.w};
        float zs[4] = {x0v.x, x0v.y, x0v.z, x0v.w};
        float as[4] = {a.x, a.y, a.z, a.w};
        float os[4];
#pragma unroll
        for (int k = 0; k < 4; ++k) {
            float reaction = -(xs[k] - 1.0f) * xs[k];
            float st = fminf(fmaxf(src * zs[k], -1.0f), 1.0f);
            os[k] = as[k] - alpha * xs[k] + beta * reaction + st * 0.1f;
        }
        ((float4*)out)[gidx] = make_float4(os[0], os[1], os[2], os[3]);
    }
}

extern "C" void kernel_launch(void* const* d_in, const int* in_sizes, int n_in,
                              void* d_out, int out_size, void* d_ws, size_t ws_size,
                              hipStream_t stream) {
    const float* x   = (const float*)d_in[1];
    const int*   ei  = (const int*)d_in[2];
    const float* ew  = (const float*)d_in[3];
    const float* x0  = (const float*)d_in[4];
    const float* alp = (const float*)d_in[5];
    const float* bet = (const float*)d_in[6];
    const float* src = (const float*)d_in[7];
    float* out = (float*)d_out;

    const int E = in_sizes[3];
    const int N = out_size / D_FEAT;
    const int* rows = ei;
    const int* cols = ei + E;

    const int NB = (N + RPB - 1) / RPB;     // 782 for N=100000 (<= MAXNB)
    const int E4 = E / 4;

    char* ws = (char*)d_ws;
    int* gcnt = (int*)ws;   ws += ((size_t)NB * 4 + 15) & ~15ull;
    int* off  = (int*)ws;   ws += ((size_t)(NB + 1) * 4 + 15) & ~15ull;
    int* cur  = (int*)ws;   ws += ((size_t)NB * 4 + 15) & ~15ull;
    uint2* recs = (uint2*)ws; ws += ((size_t)E * 8 + 15) & ~15ull;

    zero_kernel<<<(NB + 255) / 256, 256, 0, stream>>>(gcnt, NB);
    bhist_kernel<<<256, 256, 0, stream>>>(rows, gcnt, E4, NB);
    bscan_kernel<<<1, 64, 0, stream>>>(gcnt, off, cur, NB);
    binscatter_kernel<<<(E + K3_TILE - 1) / K3_TILE, K3_THREADS, 0, stream>>>(
        rows, cols, ew, alp, cur, recs, E, NB);
    bgather_kernel<<<NB, K4_THREADS, 0, stream>>>(x, x0, off, recs,
                                                  alp, bet, src, out, N);
}